// Round 1
// baseline (4392.945 us; speedup 1.0000x reference)
//
#include <hip/hip_runtime.h>
#include <math.h>

#define C_ 1024
#define H_ 512
#define D_ 256
#define M_ 16384
#define ROWS 32768
#define RT 64

// ---- m2[m] = sum_k bank[m][k]^2 : one wave per bank row ----
__global__ __launch_bounds__(256) void m2_kernel(const float* __restrict__ bank,
                                                 float* __restrict__ m2) {
  const int tid = threadIdx.x;
  const int lane = tid & 63;
  const int w = tid >> 6;
  const int row = blockIdx.x * 4 + w;
  float4 v = *reinterpret_cast<const float4*>(bank + (size_t)row * D_ + lane * 4);
  float s = v.x * v.x + v.y * v.y + v.z * v.z + v.w * v.w;
#pragma unroll
  for (int off = 1; off < 64; off <<= 1) s += __shfl_xor(s, off);
  if (lane == 0) m2[row] = s;
}

// ---- fused: MLP (64 rows) -> proj in LDS -> min-dist vs all 16384 banks ----
__global__ __launch_bounds__(256, 2) void fused_kernel(
    const float* __restrict__ F, const float* __restrict__ W1,
    const float* __restrict__ b1, const float* __restrict__ W2,
    const float* __restrict__ b2, const float* __restrict__ bank,
    const float* __restrict__ m2g, float* __restrict__ out) {
  // 80 KiB LDS, time-shared:
  //  phase 1: sH[64][68] | sF[64][20] | sW[16][64] | sW2[16][260]
  //  phase 2: sP[64][256] (proj) | sB[16][256] (bank k-chunk, transposed)
  __shared__ __align__(16) float smem[20480];
  float* sH = smem;            // 4352 floats
  float* sF = smem + 4352;     // 1280
  float* sW = smem + 5632;     // 1024
  float* sW2 = smem + 6656;    // 4160
  float* sP = smem;            // 16384
  float* sB = smem + 16384;    // 4096

  const int tid = threadIdx.x;
  const int tx = tid & 15, ty = tid >> 4;  // phase-1 16x16 map
  const size_t r0 = (size_t)blockIdx.x * RT;

  // proj accumulator: rows 4*ty+i, cols seg*64 + 4*tx + q
  float pacc[4][16];
#pragma unroll
  for (int i = 0; i < 4; ++i)
#pragma unroll
    for (int j = 0; j < 16; ++j) pacc[i][j] = 0.f;

  for (int cg = 0; cg < 8; ++cg) {  // 8 chunks of 64 h-columns
    float hacc[4][4];
#pragma unroll
    for (int i = 0; i < 4; ++i)
#pragma unroll
      for (int j = 0; j < 4; ++j) hacc[i][j] = 0.f;

    // ---- phase 1a: hchunk[64][64] = F[64][1024] @ W1[:, cg*64 .. +64) ----
    for (int kc = 0; kc < 64; ++kc) {
      {
        const int r = tid >> 2, ko = (tid & 3) << 2;
        float4 v = *reinterpret_cast<const float4*>(F + (r0 + r) * C_ + kc * 16 + ko);
        *reinterpret_cast<float4*>(sF + r * 20 + ko) = v;
      }
      {
        const int k = tid >> 4, co = (tid & 15) << 2;
        float4 v = *reinterpret_cast<const float4*>(W1 + (size_t)(kc * 16 + k) * H_ + cg * 64 + co);
        *reinterpret_cast<float4*>(sW + k * 64 + co) = v;
      }
      __syncthreads();
#pragma unroll
      for (int kkg = 0; kkg < 4; ++kkg) {
        float4 av[4];
#pragma unroll
        for (int i = 0; i < 4; ++i)
          av[i] = *reinterpret_cast<const float4*>(sF + (4 * ty + i) * 20 + kkg * 4);
#pragma unroll
        for (int e = 0; e < 4; ++e) {
          const int kk = kkg * 4 + e;
          float4 wv = *reinterpret_cast<const float4*>(sW + kk * 64 + 4 * tx);
#pragma unroll
          for (int i = 0; i < 4; ++i) {
            const float a = (&av[i].x)[e];
            hacc[i][0] += a * wv.x;
            hacc[i][1] += a * wv.y;
            hacc[i][2] += a * wv.z;
            hacc[i][3] += a * wv.w;
          }
        }
      }
      __syncthreads();
    }
    // relu + b1 -> sH
    {
      const float4 bb = *reinterpret_cast<const float4*>(b1 + cg * 64 + 4 * tx);
#pragma unroll
      for (int i = 0; i < 4; ++i) {
        float* dst = sH + (4 * ty + i) * 68 + 4 * tx;
        dst[0] = fmaxf(hacc[i][0] + bb.x, 0.f);
        dst[1] = fmaxf(hacc[i][1] + bb.y, 0.f);
        dst[2] = fmaxf(hacc[i][2] + bb.z, 0.f);
        dst[3] = fmaxf(hacc[i][3] + bb.w, 0.f);
      }
    }
    __syncthreads();

    // ---- phase 1b: pacc += hchunk @ W2[cg*64 .. +64, :] ----
    for (int ks = 0; ks < 4; ++ks) {
      {
        const int k = tid >> 4, co = (tid & 15) << 4;
        const float* src = W2 + (size_t)(cg * 64 + ks * 16 + k) * D_ + co;
#pragma unroll
        for (int q = 0; q < 4; ++q)
          *reinterpret_cast<float4*>(sW2 + k * 260 + co + 4 * q) =
              *reinterpret_cast<const float4*>(src + 4 * q);
      }
      __syncthreads();
#pragma unroll
      for (int kkg = 0; kkg < 4; ++kkg) {
        float4 hv[4];
#pragma unroll
        for (int i = 0; i < 4; ++i)
          hv[i] = *reinterpret_cast<const float4*>(sH + (4 * ty + i) * 68 + ks * 16 + kkg * 4);
#pragma unroll
        for (int e = 0; e < 4; ++e) {
          const int kk = kkg * 4 + e;
#pragma unroll
          for (int seg = 0; seg < 4; ++seg) {
            float4 wv = *reinterpret_cast<const float4*>(sW2 + kk * 260 + seg * 64 + 4 * tx);
#pragma unroll
            for (int i = 0; i < 4; ++i) {
              const float h = (&hv[i].x)[e];
              pacc[i][seg * 4 + 0] += h * wv.x;
              pacc[i][seg * 4 + 1] += h * wv.y;
              pacc[i][seg * 4 + 2] += h * wv.z;
              pacc[i][seg * 4 + 3] += h * wv.w;
            }
          }
        }
      }
      __syncthreads();
    }
  }

  // ---- write proj (+b2) into sP (overwrites phase-1 regions; all dead) ----
#pragma unroll
  for (int seg = 0; seg < 4; ++seg) {
    const float4 bb = *reinterpret_cast<const float4*>(b2 + seg * 64 + 4 * tx);
#pragma unroll
    for (int i = 0; i < 4; ++i) {
      float* dst = sP + (4 * ty + i) * 256 + seg * 64 + 4 * tx;
      dst[0] = pacc[i][seg * 4 + 0] + bb.x;
      dst[1] = pacc[i][seg * 4 + 1] + bb.y;
      dst[2] = pacc[i][seg * 4 + 2] + bb.z;
      dst[3] = pacc[i][seg * 4 + 3] + bb.w;
    }
  }
  __syncthreads();

  const int tx2 = tid & 31, ty2 = tid >> 5;  // phase-2 32x8 map

  // ---- x2 per row (into sB scratch, then registers) ----
  {
    const int row = tid & 63, seg = tid >> 6;
    float s = 0.f;
#pragma unroll
    for (int k4 = 0; k4 < 16; ++k4) {
      float4 v = *reinterpret_cast<const float4*>(sP + row * 256 + seg * 64 + k4 * 4);
      s += v.x * v.x + v.y * v.y + v.z * v.z + v.w * v.w;
    }
    sB[seg * 64 + row] = s;
  }
  __syncthreads();
  if (tid < 64) sB[256 + tid] = sB[tid] + sB[64 + tid] + sB[128 + tid] + sB[192 + tid];
  __syncthreads();
  float x2v[8];
#pragma unroll
  for (int i = 0; i < 8; ++i) x2v[i] = sB[256 + 8 * ty2 + i];
  __syncthreads();

  // ---- phase 2: min over banks of (m2 - 2*proj.bank) ----
  float minv[8];
#pragma unroll
  for (int i = 0; i < 8; ++i) minv[i] = 3.0e38f;

  for (int tile = 0; tile < 64; ++tile) {  // 256 banks per tile
    float acc[8][8];
#pragma unroll
    for (int i = 0; i < 8; ++i)
#pragma unroll
      for (int j = 0; j < 8; ++j) acc[i][j] = 0.f;
    const float* brow = bank + ((size_t)tile * 256 + tid) * D_;
    for (int kc = 0; kc < 16; ++kc) {  // K chunks of 16
      // stage sB[k][m] transposed: thread = one bank row
#pragma unroll
      for (int q = 0; q < 4; ++q) {
        float4 v = *reinterpret_cast<const float4*>(brow + kc * 16 + q * 4);
        sB[(q * 4 + 0) * 256 + tid] = v.x;
        sB[(q * 4 + 1) * 256 + tid] = v.y;
        sB[(q * 4 + 2) * 256 + tid] = v.z;
        sB[(q * 4 + 3) * 256 + tid] = v.w;
      }
      __syncthreads();
#pragma unroll
      for (int kkg = 0; kkg < 4; ++kkg) {
        float4 pv[8];
#pragma unroll
        for (int i = 0; i < 8; ++i)
          pv[i] = *reinterpret_cast<const float4*>(sP + (8 * ty2 + i) * 256 + kc * 16 + kkg * 4);
#pragma unroll
        for (int e = 0; e < 4; ++e) {
          const int kk = kkg * 4 + e;
          float4 b0 = *reinterpret_cast<const float4*>(sB + kk * 256 + 4 * tx2);
          float4 b1v = *reinterpret_cast<const float4*>(sB + kk * 256 + 128 + 4 * tx2);
#pragma unroll
          for (int i = 0; i < 8; ++i) {
            const float p = (&pv[i].x)[e];
            acc[i][0] += p * b0.x;
            acc[i][1] += p * b0.y;
            acc[i][2] += p * b0.z;
            acc[i][3] += p * b0.w;
            acc[i][4] += p * b1v.x;
            acc[i][5] += p * b1v.y;
            acc[i][6] += p * b1v.z;
            acc[i][7] += p * b1v.w;
          }
        }
      }
      __syncthreads();
    }
    // per-tile epilogue: fold into running min
#pragma unroll
    for (int j = 0; j < 8; ++j) {
      const int ml = (j < 4) ? (4 * tx2 + j) : (128 + 4 * tx2 + j - 4);
      const float mv = m2g[tile * 256 + ml];
#pragma unroll
      for (int i = 0; i < 8; ++i) minv[i] = fminf(minv[i], mv - 2.f * acc[i][j]);
    }
  }

  // ---- reduce min across the 32 tx2 lanes, finalize ----
#pragma unroll
  for (int i = 0; i < 8; ++i) {
    float v = minv[i];
#pragma unroll
    for (int off = 1; off < 32; off <<= 1) v = fminf(v, __shfl_xor(v, off));
    minv[i] = v;
  }
  if (tx2 == 0) {
#pragma unroll
    for (int i = 0; i < 8; ++i) {
      const float d2 = x2v[i] + minv[i];
      out[r0 + 8 * ty2 + i] = sqrtf(fmaxf(d2, 0.f));
    }
  }
}

extern "C" void kernel_launch(void* const* d_in, const int* in_sizes, int n_in,
                              void* d_out, int out_size, void* d_ws, size_t ws_size,
                              hipStream_t stream) {
  const float* F = (const float*)d_in[0];
  const float* W1 = (const float*)d_in[1];
  const float* b1 = (const float*)d_in[2];
  const float* W2 = (const float*)d_in[3];
  const float* b2 = (const float*)d_in[4];
  const float* bank = (const float*)d_in[5];
  float* m2 = (float*)d_ws;  // 16384 floats = 64 KiB
  float* out = (float*)d_out;

  m2_kernel<<<M_ / 4, 256, 0, stream>>>(bank, m2);
  fused_kernel<<<ROWS / RT, 256, 0, stream>>>(F, W1, b1, W2, b2, bank, m2, out);
}

// Round 2
// 310.019 us; speedup vs baseline: 14.1699x; 14.1699x over previous
//
#include <hip/hip_runtime.h>
#include <math.h>

typedef __bf16 bf16;
typedef __attribute__((ext_vector_type(8))) __bf16 bf16x8;
typedef __attribute__((ext_vector_type(4))) __bf16 bf16x4;
typedef __attribute__((ext_vector_type(4))) float f32x4;

typedef __attribute__((address_space(1))) const void gvoid;
typedef __attribute__((address_space(3))) void lvoid;
#define GLL(g, l) __builtin_amdgcn_global_load_lds((gvoid*)(g), (lvoid*)(l), 16, 0, 0)
#define MFMA(a, b, c) __builtin_amdgcn_mfma_f32_16x16x32_bf16((a), (b), (c), 0, 0, 0)

__device__ __forceinline__ int swz128(int row, int kb) { return kb ^ ((row & 7) << 4); }

// ---------------- prep: W1 [1024][512] -> W1t bf16 [512][1024]; W2 [512][256] -> W2t [256][512]
__global__ __launch_bounds__(256) void prep_w(const float* __restrict__ W1,
                                              const float* __restrict__ W2,
                                              bf16* __restrict__ W1t, bf16* __restrict__ W2t) {
  const int t = blockIdx.x * 256 + threadIdx.x;
  if (t < 512 * 1024) {
    const int h = t & 511, k = t >> 9;
    W1t[h * 1024 + k] = (bf16)W1[k * 512 + h];
  } else {
    const int u = t - 512 * 1024;
    const int e = u & 255, k = u >> 8;
    W2t[e * 512 + k] = (bf16)W2[k * 256 + e];
  }
}

// ---------------- prep: bank fp32 [16384][256] -> bf16 + m2
__global__ __launch_bounds__(256) void prep_bank(const float* __restrict__ bank,
                                                 bf16* __restrict__ BB, float* __restrict__ m2) {
  const int tid = threadIdx.x, lane = tid & 63, w = tid >> 6;
  const int row = blockIdx.x * 4 + w;
  const float4 v = *reinterpret_cast<const float4*>(bank + (size_t)row * 256 + lane * 4);
  float s = v.x * v.x + v.y * v.y + v.z * v.z + v.w * v.w;
#pragma unroll
  for (int off = 1; off < 64; off <<= 1) s += __shfl_xor(s, off);
  bf16x4 p;
  p[0] = (bf16)v.x; p[1] = (bf16)v.y; p[2] = (bf16)v.z; p[3] = (bf16)v.w;
  *reinterpret_cast<bf16x4*>(BB + (size_t)row * 256 + lane * 4) = p;
  if (lane == 0) m2[row] = s;
}

// ---------------- mlp1: H[32768][512] = relu(F @ W1 + b1), bf16 out
__global__ __launch_bounds__(512, 2) void mlp1_kernel(const float* __restrict__ F,
                                                      const bf16* __restrict__ W1t,
                                                      const float* __restrict__ b1,
                                                      bf16* __restrict__ H) {
  __shared__ __align__(16) char smem[81920];
  char* sA = smem;          // F chunk bf16 [128 rows][128B], swizzled
  char* sB = smem + 16384;  // W1t chunk [512 n][128B], swizzled

  const int tid = threadIdx.x;
  const int w = tid >> 6, lane = tid & 63;
  const int wm = w >> 2, wn = w & 3;
  const int lr = lane & 15, lk = lane >> 4;
  const size_t r0 = (size_t)blockIdx.x * 128;

  f32x4 acc[4][8];
  const f32x4 z = {0.f, 0.f, 0.f, 0.f};
#pragma unroll
  for (int m = 0; m < 4; ++m)
#pragma unroll
    for (int n = 0; n < 8; ++n) acc[m][n] = z;

  for (int kc = 0; kc < 16; ++kc) {
    // stage F chunk (fp32 -> bf16, swizzled ds_write)
    {
      const int fr = tid >> 2, kg = (tid & 3) * 16;
      const float* fsrc = F + (r0 + fr) * 1024 + kc * 64 + kg;
      const float4 f0 = *reinterpret_cast<const float4*>(fsrc);
      const float4 f1 = *reinterpret_cast<const float4*>(fsrc + 4);
      const float4 f2 = *reinterpret_cast<const float4*>(fsrc + 8);
      const float4 f3 = *reinterpret_cast<const float4*>(fsrc + 12);
      bf16x8 p0, p1;
      p0[0] = (bf16)f0.x; p0[1] = (bf16)f0.y; p0[2] = (bf16)f0.z; p0[3] = (bf16)f0.w;
      p0[4] = (bf16)f1.x; p0[5] = (bf16)f1.y; p0[6] = (bf16)f1.z; p0[7] = (bf16)f1.w;
      p1[0] = (bf16)f2.x; p1[1] = (bf16)f2.y; p1[2] = (bf16)f2.z; p1[3] = (bf16)f2.w;
      p1[4] = (bf16)f3.x; p1[5] = (bf16)f3.y; p1[6] = (bf16)f3.z; p1[7] = (bf16)f3.w;
      const int bb = kg * 2;
      *(bf16x8*)(sA + fr * 128 + swz128(fr, bb)) = p0;
      *(bf16x8*)(sA + fr * 128 + swz128(fr, bb + 16)) = p1;
    }
    // stage W1t chunk via global_load_lds (pre-swizzled source)
#pragma unroll
    for (int i = 0; i < 8; ++i) {
      const int o = (w * 8 + i) * 1024 + lane * 16;
      const int n = o >> 7, b = o & 127;
      GLL((const char*)W1t + n * 2048 + kc * 128 + swz128(n, b), sB + (w * 8 + i) * 1024);
    }
    __syncthreads();
#pragma unroll
    for (int ks = 0; ks < 2; ++ks) {
      bf16x8 av[4];
#pragma unroll
      for (int Mt = 0; Mt < 4; ++Mt) {
        const int row = wm * 64 + Mt * 16 + lr;
        av[Mt] = *(const bf16x8*)(sA + row * 128 + swz128(row, ks * 64 + lk * 16));
      }
#pragma unroll
      for (int Nt = 0; Nt < 8; ++Nt) {
        const int n = wn * 128 + Nt * 16 + lr;
        const bf16x8 bv = *(const bf16x8*)(sB + n * 128 + swz128(n, ks * 64 + lk * 16));
#pragma unroll
        for (int Mt = 0; Mt < 4; ++Mt) acc[Mt][Nt] = MFMA(av[Mt], bv, acc[Mt][Nt]);
      }
    }
    __syncthreads();
  }
  // epilogue: bias + relu + bf16 store
#pragma unroll
  for (int Nt = 0; Nt < 8; ++Nt) {
    const int col = wn * 128 + Nt * 16 + lr;
    const float bias = b1[col];
#pragma unroll
    for (int Mt = 0; Mt < 4; ++Mt) {
      const size_t rowb = r0 + wm * 64 + Mt * 16 + lk * 4;
#pragma unroll
      for (int q = 0; q < 4; ++q)
        H[(rowb + q) * 512 + col] = (bf16)fmaxf(acc[Mt][Nt][q] + bias, 0.f);
    }
  }
}

// ---------------- mlp2: PROJ[32768][256] bf16 = H @ W2 + b2 ; X2[32768] fp32
__global__ __launch_bounds__(512, 2) void mlp2_kernel(const bf16* __restrict__ H,
                                                      const bf16* __restrict__ W2t,
                                                      const float* __restrict__ b2,
                                                      bf16* __restrict__ PROJ,
                                                      float* __restrict__ X2) {
  __shared__ __align__(16) char smem[51200];
  char* sA = smem;                        // H chunk [128][128B] swizzled
  char* sB = smem + 16384;                // W2t chunk [256][128B] swizzled
  float* sX2 = (float*)(smem + 49152);    // [4][128]

  const int tid = threadIdx.x;
  const int w = tid >> 6, lane = tid & 63;
  const int wm = w >> 2, wn = w & 3;
  const int lr = lane & 15, lk = lane >> 4;
  const size_t r0 = (size_t)blockIdx.x * 128;

  f32x4 acc[4][4];
  const f32x4 z = {0.f, 0.f, 0.f, 0.f};
#pragma unroll
  for (int m = 0; m < 4; ++m)
#pragma unroll
    for (int n = 0; n < 4; ++n) acc[m][n] = z;

  for (int kc = 0; kc < 8; ++kc) {
#pragma unroll
    for (int i = 0; i < 2; ++i) {
      const int o = (w * 2 + i) * 1024 + lane * 16;
      const int row = o >> 7, b = o & 127;
      GLL((const char*)H + (r0 + row) * 1024 + kc * 128 + swz128(row, b), sA + (w * 2 + i) * 1024);
    }
#pragma unroll
    for (int i = 0; i < 4; ++i) {
      const int o = (w * 4 + i) * 1024 + lane * 16;
      const int n = o >> 7, b = o & 127;
      GLL((const char*)W2t + n * 1024 + kc * 128 + swz128(n, b), sB + (w * 4 + i) * 1024);
    }
    __syncthreads();
#pragma unroll
    for (int ks = 0; ks < 2; ++ks) {
      bf16x8 av[4];
#pragma unroll
      for (int Mt = 0; Mt < 4; ++Mt) {
        const int row = wm * 64 + Mt * 16 + lr;
        av[Mt] = *(const bf16x8*)(sA + row * 128 + swz128(row, ks * 64 + lk * 16));
      }
#pragma unroll
      for (int Nt = 0; Nt < 4; ++Nt) {
        const int n = wn * 64 + Nt * 16 + lr;
        const bf16x8 bv = *(const bf16x8*)(sB + n * 128 + swz128(n, ks * 64 + lk * 16));
#pragma unroll
        for (int Mt = 0; Mt < 4; ++Mt) acc[Mt][Nt] = MFMA(av[Mt], bv, acc[Mt][Nt]);
      }
    }
    __syncthreads();
  }
  // epilogue: +b2, store bf16 proj, accumulate x2
  float x2p[4][4];
#pragma unroll
  for (int m = 0; m < 4; ++m)
#pragma unroll
    for (int q = 0; q < 4; ++q) x2p[m][q] = 0.f;
#pragma unroll
  for (int Nt = 0; Nt < 4; ++Nt) {
    const int col = wn * 64 + Nt * 16 + lr;
    const float bias = b2[col];
#pragma unroll
    for (int Mt = 0; Mt < 4; ++Mt) {
      const size_t rowb = r0 + wm * 64 + Mt * 16 + lk * 4;
#pragma unroll
      for (int q = 0; q < 4; ++q) {
        const float p = acc[Mt][Nt][q] + bias;
        PROJ[(rowb + q) * 256 + col] = (bf16)p;
        x2p[Mt][q] += p * p;
      }
    }
  }
#pragma unroll
  for (int Mt = 0; Mt < 4; ++Mt)
#pragma unroll
    for (int q = 0; q < 4; ++q) {
      float v = x2p[Mt][q];
      v += __shfl_xor(v, 1); v += __shfl_xor(v, 2);
      v += __shfl_xor(v, 4); v += __shfl_xor(v, 8);
      x2p[Mt][q] = v;
    }
  __syncthreads();
  if (lr == 0) {
#pragma unroll
    for (int Mt = 0; Mt < 4; ++Mt)
#pragma unroll
      for (int q = 0; q < 4; ++q)
        sX2[wn * 128 + wm * 64 + Mt * 16 + lk * 4 + q] = x2p[Mt][q];
  }
  __syncthreads();
  if (tid < 128)
    X2[r0 + tid] = sX2[tid] + sX2[128 + tid] + sX2[256 + tid] + sX2[384 + tid];
}

// ---------------- dist: out[r] = sqrt(max(x2[r] + min_m(m2[m] - 2*proj[r].bank[m]), 0))
__global__ __launch_bounds__(512, 2) void dist_kernel(const bf16* __restrict__ PROJ,
                                                      const bf16* __restrict__ BB,
                                                      const float* __restrict__ m2,
                                                      const float* __restrict__ X2,
                                                      float* __restrict__ out) {
  __shared__ __align__(16) char smem[133120];
  char* buf0 = smem;
  char* buf1 = smem + 65536;
  float* minbuf = (float*)(smem + 131072);  // [4][128]

  const int tid = threadIdx.x;
  const int w = tid >> 6, lane = tid & 63;
  const int wm = w >> 2, wn = w & 3;
  const int lr = lane & 15, lk = lane >> 4;
  const size_t r0 = (size_t)blockIdx.x * 128;

  // A (proj) fragments held in registers for the whole N loop
  bf16x8 A[4][8];
#pragma unroll
  for (int Mt = 0; Mt < 4; ++Mt)
#pragma unroll
    for (int ks = 0; ks < 8; ++ks) {
      const size_t row = r0 + wm * 64 + Mt * 16 + lr;
      A[Mt][ks] = *(const bf16x8*)(PROJ + row * 256 + ks * 32 + lk * 8);
    }

  // stage tile 0 (banks 0..127, full K) into buf0
#pragma unroll
  for (int i = 0; i < 8; ++i) {
    const int o = (w * 8 + i) * 1024 + lane * 16;
    const int n = o >> 9, b = o & 511;
    GLL((const char*)BB + (size_t)n * 512 + (b ^ ((n & 7) << 4)), buf0 + (w * 8 + i) * 1024);
  }
  __syncthreads();

  float minv[4][4];
#pragma unroll
  for (int m = 0; m < 4; ++m)
#pragma unroll
    for (int q = 0; q < 4; ++q) minv[m][q] = 3.0e38f;

  const f32x4 z = {0.f, 0.f, 0.f, 0.f};
  for (int t = 0; t < 128; ++t) {
    char* cur = (t & 1) ? buf1 : buf0;
    char* nxt = (t & 1) ? buf0 : buf1;
    if (t < 127) {
#pragma unroll
      for (int i = 0; i < 8; ++i) {
        const int o = (w * 8 + i) * 1024 + lane * 16;
        const int n = o >> 9, b = o & 511;
        GLL((const char*)BB + ((size_t)(t + 1) * 128 + n) * 512 + (b ^ ((n & 7) << 4)),
            nxt + (w * 8 + i) * 1024);
      }
    }
    f32x4 acc[4][2];
#pragma unroll
    for (int m = 0; m < 4; ++m)
#pragma unroll
      for (int n = 0; n < 2; ++n) acc[m][n] = z;
#pragma unroll
    for (int ks = 0; ks < 8; ++ks) {
#pragma unroll
      for (int Nt = 0; Nt < 2; ++Nt) {
        const int n = wn * 32 + Nt * 16 + lr;
        const bf16x8 bv =
            *(const bf16x8*)(cur + n * 512 + ((ks * 64 + lk * 16) ^ ((n & 7) << 4)));
#pragma unroll
        for (int Mt = 0; Mt < 4; ++Mt) acc[Mt][Nt] = MFMA(A[Mt][ks], bv, acc[Mt][Nt]);
      }
    }
    // min epilogue (VALU, overlaps next tile's loads)
#pragma unroll
    for (int Nt = 0; Nt < 2; ++Nt) {
      const float mv = m2[t * 128 + wn * 32 + Nt * 16 + lr];
#pragma unroll
      for (int Mt = 0; Mt < 4; ++Mt)
#pragma unroll
        for (int q = 0; q < 4; ++q)
          minv[Mt][q] = fminf(minv[Mt][q], fmaf(-2.f, acc[Mt][Nt][q], mv));
    }
    __syncthreads();
  }

  // reduce min over the 16 col-lanes
#pragma unroll
  for (int Mt = 0; Mt < 4; ++Mt)
#pragma unroll
    for (int q = 0; q < 4; ++q) {
      float v = minv[Mt][q];
      v = fminf(v, __shfl_xor(v, 1)); v = fminf(v, __shfl_xor(v, 2));
      v = fminf(v, __shfl_xor(v, 4)); v = fminf(v, __shfl_xor(v, 8));
      minv[Mt][q] = v;
    }
  if (lr == 0) {
#pragma unroll
    for (int Mt = 0; Mt < 4; ++Mt)
#pragma unroll
      for (int q = 0; q < 4; ++q)
        minbuf[wn * 128 + wm * 64 + Mt * 16 + lk * 4 + q] = minv[Mt][q];
  }
  __syncthreads();
  if (tid < 128) {
    const float m = fminf(fminf(minbuf[tid], minbuf[128 + tid]),
                          fminf(minbuf[256 + tid], minbuf[384 + tid]));
    const float d2 = X2[r0 + tid] + m;
    out[r0 + tid] = sqrtf(fmaxf(d2, 0.f));
  }
}

extern "C" void kernel_launch(void* const* d_in, const int* in_sizes, int n_in,
                              void* d_out, int out_size, void* d_ws, size_t ws_size,
                              hipStream_t stream) {
  const float* F = (const float*)d_in[0];
  const float* W1 = (const float*)d_in[1];
  const float* b1 = (const float*)d_in[2];
  const float* W2 = (const float*)d_in[3];
  const float* b2 = (const float*)d_in[4];
  const float* bank = (const float*)d_in[5];
  float* out = (float*)d_out;

  char* ws = (char*)d_ws;
  bf16* BB = (bf16*)(ws + 0);            //  8,388,608 B
  float* m2 = (float*)(ws + 8388608);    //     65,536 B
  bf16* W1t = (bf16*)(ws + 8454144);     //  1,048,576 B
  bf16* W2t = (bf16*)(ws + 9502720);     //    262,144 B
  bf16* H = (bf16*)(ws + 9764864);       // 33,554,432 B
  bf16* PROJ = (bf16*)(ws + 43319296);   // 16,777,216 B
  float* X2 = (float*)(ws + 60096512);   //    131,072 B  -> total 60,227,584 B

  prep_w<<<2560, 256, 0, stream>>>(W1, W2, W1t, W2t);
  prep_bank<<<4096, 256, 0, stream>>>(bank, BB, m2);
  mlp1_kernel<<<256, 512, 0, stream>>>(F, W1t, b1, H);
  mlp2_kernel<<<256, 512, 0, stream>>>(H, W2t, b2, PROJ, X2);
  dist_kernel<<<256, 512, 0, stream>>>(PROJ, BB, m2, X2, out);
}